// Round 4
// baseline (253.115 us; speedup 1.0000x reference)
//
#include <hip/hip_runtime.h>
#include <math.h>

// out[b,c,n] = softmax_n(max_c x[b,c,n]) * x[b,c,n]   (x: [256,64,2048] fp32)
//
// R6: the 512MiB ws poison fills (~80us) are unconditional harness overhead —
// they appear even with no d_ws use. Controllable part = our kernels (~90us).
// R5's K_A kept the 1-block-per-row structure (1 block/CU) for the max phase,
// which historically pins reads at ~2.9 TB/s. This version streams the max
// phase at full grid: 2048 blocks (8/CU), each a 64-col x 64-chan slice with
// 4 waves striping channels, LDS-combining partial maxes. xm staged in
// out[b, ch0, :]; softmax kernel turns it into the gate in place and
// replicates at channels {0,16,32,48}; mul kernel (race-free per R5)
// consumes and overwrites. 3 dispatches, no workspace.

#define B_DIM 256
#define C_DIM 64
#define N_DIM 2048
#define COLS4 (N_DIM / 4)          // 512 float4 columns per row
#define ROW4  (C_DIM * COLS4)      // 32768 float4 per batch row

// ---------------- K1: xm[b,n] = max_c x[b,c,n] -> out[b,0,:] ----------------
// 2048 blocks = 256 rows x 8 col-slices, 256 threads (4 waves).
// Wave w handles channels {w, w+4, ..., w+60} for 64 columns: each load is a
// contiguous 1KB line; 8 blocks/CU x 4 waves = full occupancy of read streams.
__global__ __launch_bounds__(256)
void max_kernel(const float* __restrict__ x, float* __restrict__ out) {
    const int bid  = blockIdx.x;
    const int b    = bid >> 3;
    const int s    = bid & 7;
    const int t    = threadIdx.x;
    const int lane = t & 63;
    const int w    = t >> 6;                 // 0..3
    const int col  = (s << 6) + lane;        // 0..511

    const float4* __restrict__ xb = (const float4*)x + (size_t)b * ROW4;

    float4 m = make_float4(-INFINITY, -INFINITY, -INFINITY, -INFINITY);
    #pragma unroll
    for (int i = 0; i < 16; ++i) {
        const int c = w + (i << 2);          // channel: w, w+4, ..., w+60
        float4 v = xb[(size_t)c * COLS4 + col];
        m.x = fmaxf(m.x, v.x); m.y = fmaxf(m.y, v.y);
        m.z = fmaxf(m.z, v.z); m.w = fmaxf(m.w, v.w);
    }

    __shared__ float4 pm[4][64];             // 4 KB
    pm[w][lane] = m;
    __syncthreads();

    if (t < 64) {
        float4 a = pm[0][t], b1 = pm[1][t], c1 = pm[2][t], d = pm[3][t];
        float4 r;
        r.x = fmaxf(fmaxf(a.x, b1.x), fmaxf(c1.x, d.x));
        r.y = fmaxf(fmaxf(a.y, b1.y), fmaxf(c1.y, d.y));
        r.z = fmaxf(fmaxf(a.z, b1.z), fmaxf(c1.z, d.z));
        r.w = fmaxf(fmaxf(a.w, b1.w), fmaxf(c1.w, d.w));
        // stage xm into out[b, channel 0, cols s*64..s*64+63]
        ((float4*)out)[(size_t)b * ROW4 + (s << 6) + t] = r;
    }
}

// ---------------- K2: gate = softmax(xm), replicate to ch {0,16,32,48} ------
// 256 blocks x 256 threads (4 waves), thread t owns columns t and t+256.
// Each thread reads only locations it alone overwrites -> no hazards.
__global__ __launch_bounds__(256)
void softmax_kernel(float* __restrict__ out) {
    const int b    = blockIdx.x;
    const int t    = threadIdx.x;
    const int lane = t & 63;
    const int wid  = t >> 6;                 // 0..3
    __shared__ float sred[8];

    float4* ob = (float4*)out + (size_t)b * ROW4;
    float4 a0 = ob[t];
    float4 a1 = ob[t + 256];

    float tm = fmaxf(fmaxf(fmaxf(a0.x, a0.y), fmaxf(a0.z, a0.w)),
                     fmaxf(fmaxf(a1.x, a1.y), fmaxf(a1.z, a1.w)));
    #pragma unroll
    for (int off = 32; off > 0; off >>= 1)
        tm = fmaxf(tm, __shfl_down(tm, off, 64));
    if (lane == 0) sred[wid] = tm;
    __syncthreads();
    const float M = fmaxf(fmaxf(sred[0], sred[1]), fmaxf(sred[2], sred[3]));

    float4 e0, e1;
    e0.x = __expf(a0.x - M); e0.y = __expf(a0.y - M);
    e0.z = __expf(a0.z - M); e0.w = __expf(a0.w - M);
    e1.x = __expf(a1.x - M); e1.y = __expf(a1.y - M);
    e1.z = __expf(a1.z - M); e1.w = __expf(a1.w - M);
    float ts = ((e0.x + e0.y) + (e0.z + e0.w)) + ((e1.x + e1.y) + (e1.z + e1.w));
    #pragma unroll
    for (int off = 32; off > 0; off >>= 1)
        ts += __shfl_down(ts, off, 64);
    if (lane == 0) sred[4 + wid] = ts;
    __syncthreads();
    const float inv = 1.0f / ((sred[4] + sred[5]) + (sred[6] + sred[7]));

    float4 g0, g1;
    g0.x = e0.x * inv; g0.y = e0.y * inv; g0.z = e0.z * inv; g0.w = e0.w * inv;
    g1.x = e1.x * inv; g1.y = e1.y * inv; g1.z = e1.z * inv; g1.w = e1.w * inv;
    #pragma unroll
    for (int g = 0; g < 4; ++g) {
        ob[(size_t)(g * 16) * COLS4 + t]       = g0;
        ob[(size_t)(g * 16) * COLS4 + t + 256] = g1;
    }
}

// ---------------- K3: out = gate * x ----------------
// 1024 blocks = 256 rows x 4 channel-groups (16 channels each), 512 threads.
// Each block reads ITS gate copy (channel g*16, the first it overwrites).
__global__ __launch_bounds__(512)
void mul_kernel(const float* __restrict__ x, float* __restrict__ out) {
    const int bid = blockIdx.x;
    const int b   = bid >> 2;
    const int g   = bid & 3;
    const int col = threadIdx.x;             // 0..511

    const size_t rbase = (size_t)b * ROW4;
    const float4* __restrict__ x4 = (const float4*)x + rbase;
    float4* o4 = (float4*)out + rbase;

    const int cbase = g * 16;
    const float4 gv = o4[(size_t)cbase * COLS4 + col];   // this block's copy
    __syncthreads();                          // all reads before any write

    #pragma unroll 4
    for (int c = 0; c < 16; ++c) {
        const size_t idx = (size_t)(cbase + c) * COLS4 + col;
        float4 v = x4[idx];
        float4 o;
        o.x = v.x * gv.x; o.y = v.y * gv.y;
        o.z = v.z * gv.z; o.w = v.w * gv.w;
        o4[idx] = o;
    }
}

extern "C" void kernel_launch(void* const* d_in, const int* in_sizes, int n_in,
                              void* d_out, int out_size, void* d_ws, size_t ws_size,
                              hipStream_t stream) {
    const float* x = (const float*)d_in[0];
    float* out = (float*)d_out;
    max_kernel<<<B_DIM * 8, 256, 0, stream>>>(x, out);
    softmax_kernel<<<B_DIM, 256, 0, stream>>>(out);
    mul_kernel<<<B_DIM * 4, 512, 0, stream>>>(x, out);
}